// Round 2
// baseline (448.551 us; speedup 1.0000x reference)
//
#include <hip/hip_runtime.h>
#include <hip/hip_bf16.h>

#define NTIME   2000
#define NBATCH  128
#define INSIZE  256
#define NOUT    40
#define NROWS   (NTIME * NBATCH)   // 256000
#define CCHUNK  80                 // parallel-scan chunks
#define LSTEP   25                 // steps per chunk; CCHUNK*LSTEP == NTIME

typedef __attribute__((ext_vector_type(8))) short  short8;   // 8 bf16 = 4 VGPRs
typedef __attribute__((ext_vector_type(4))) float  float4v;

#define L2E 1.4426950408889634f
#define LN2 0.6931471805599453f

__device__ __forceinline__ float fexp2(float x){ return __builtin_amdgcn_exp2f(x); } // v_exp_f32 (2^x)
__device__ __forceinline__ float flog2(float x){ return __builtin_amdgcn_logf(x);  } // v_log_f32 (log2)

// fp32 -> bf16 with round-to-nearest-even (bit arithmetic; no lib call)
__device__ __forceinline__ short f2bf(float f) {
    unsigned u = __float_as_uint(f);
    unsigned r = u + 0x7fffu + ((u >> 16) & 1u);
    return (short)(r >> 16);
}

// ---------------------------------------------------------------- prep: W fp32 -> bf16, padded 48x256
__global__ __launch_bounds__(256) void prep_w(const float* __restrict__ W,
                                              short* __restrict__ Wb)
{
    int idx = blockIdx.x * 256 + threadIdx.x;   // 48*256 = 12288
    int n = idx >> 8, k = idx & 255;
    float v = (n < NOUT) ? W[n * INSIZE + k] : 0.f;
    Wb[idx] = f2bf(v);
}

// ---------------------------------------------------------------- GEMM + activations
// block = 256 threads = 4 waves; block computes 128 rows x all 40 outputs.
// wave w: rows [blk*128 + w*32, +32), as 2 m-tiles of 16; 3 n-tiles of 16 (48 padded).
__global__ __launch_bounds__(256) void gemm_act(const float* __restrict__ x,
                                                const short* __restrict__ Wb,
                                                const float* __restrict__ bias,
                                                float* __restrict__ out)
{
    const int tid  = threadIdx.x;
    const int wave = tid >> 6, lane = tid & 63;
    const int l16  = lane & 15, quad = lane >> 4;
    const long rowBase = (long)blockIdx.x * 128 + wave * 32;

    float4v acc[2][3];
#pragma unroll
    for (int mi = 0; mi < 2; ++mi)
#pragma unroll
        for (int ni = 0; ni < 3; ++ni)
            acc[mi][ni] = (float4v){0.f, 0.f, 0.f, 0.f};

    const float* xp0 = x + (rowBase + l16) * (long)INSIZE + quad * 8;
    const float* xp1 = xp0 + 16 * INSIZE;
    const short* wp = Wb + l16 * INSIZE + quad * 8;

#pragma unroll
    for (int s = 0; s < 8; ++s) {          // K = 256 = 8 stages of 32
        short8 afrag[2];
#pragma unroll
        for (int mi = 0; mi < 2; ++mi) {
            const float* xp = (mi ? xp1 : xp0) + s * 32;
            float4v xa = *(const float4v*)xp;
            float4v xb = *(const float4v*)(xp + 4);
            short8 a;
            a[0] = f2bf(xa[0]); a[1] = f2bf(xa[1]); a[2] = f2bf(xa[2]); a[3] = f2bf(xa[3]);
            a[4] = f2bf(xb[0]); a[5] = f2bf(xb[1]); a[6] = f2bf(xb[2]); a[7] = f2bf(xb[3]);
            afrag[mi] = a;
        }
#pragma unroll
        for (int ni = 0; ni < 3; ++ni) {
            short8 bfrag = *(const short8*)(wp + ni * 16 * INSIZE + s * 32);
            acc[0][ni] = __builtin_amdgcn_mfma_f32_16x16x32_bf16(afrag[0], bfrag, acc[0][ni], 0, 0, 0);
            acc[1][ni] = __builtin_amdgcn_mfma_f32_16x16x32_bf16(afrag[1], bfrag, acc[1][ni], 0, 0, 0);
        }
    }

    // epilogue: C/D layout col = lane&15, row = quad*4 + reg
#pragma unroll
    for (int mi = 0; mi < 2; ++mi) {
        long row0 = rowBase + mi * 16 + quad * 4;
#pragma unroll
        for (int ni = 0; ni < 3; ++ni) {
            int o = ni * 16 + l16;
            if (o >= NOUT) continue;
            float bv = bias[o];
#pragma unroll
            for (int r = 0; r < 4; ++r) {
                float y = acc[mi][ni][r] + bv;
                float val;
                if (o < 8) {
                    // softplus(y) = max(y,0) + ln2*log2(1 + 2^(-|y|*log2e))
                    float sp = fmaxf(y, 0.f) + LN2 * flog2(1.f + fexp2(-fabsf(y) * L2E));
                    val = (o < 4 ? 1.0f : 0.1f) + sp;
                } else {
                    float e = fexp2(2.f * fabsf(y) * L2E);    // e^{2|y|}
                    float t = 1.f - 2.f / (e + 1.f);
                    val = 5.f * copysignf(t, y);
                }
                out[(row0 + r) * NOUT + o] = val;
            }
        }
    }
}

// ---------------------------------------------------------------- chunked parallel scan (log-semiring)
// 8 lanes per (batch, chunk): lane j0 carries column j0 of the chunk's 8x8 matrix.
// base-2 domain: g = f*log2e; u = w*log2e folded into the fma.
__global__ __launch_bounds__(256) void scan_chunks(const float* __restrict__ out,
                                                   float* __restrict__ chunkM)
{
    const int tid   = threadIdx.x;
    const int g     = tid >> 3, j0 = tid & 7;
    const int c     = blockIdx.x >> 2;                    // 4 blocks per chunk
    const int batch = ((blockIdx.x & 3) << 5) + g;        // 32 batches per block
    const int t0    = c * LSTEP;

    float m[8];
#pragma unroll
    for (int i = 0; i < 8; ++i) m[i] = (i == j0) ? 0.f : -1e30f;

    const float* p = out + ((size_t)(t0 * NBATCH + batch) * NOUT + 8);
    float4v w[8];
#pragma unroll
    for (int q = 0; q < 8; ++q) w[q] = *(const float4v*)(p + q * 4);

    for (int step = 0; step < LSTEP; ++step) {
        const float* pn = (step < LSTEP - 1) ? (p + NBATCH * NOUT) : p;  // prefetch (clamped)
        float4v wn[8];
#pragma unroll
        for (int q = 0; q < 8; ++q) wn[q] = *(const float4v*)(pn + q * 4);

        const float* wv = (const float*)&w[0];
        float nm[8];
#pragma unroll
        for (int i = 0; i < 4; ++i) {
            float s[8];
#pragma unroll
            for (int k = 0; k < 8; ++k) s[k] = fmaf(wv[i * 8 + k], L2E, m[k]);
            // stay: sources {i, i+4}
            float a = s[i], b2 = s[i + 4];
            float mx2 = fmaxf(a, b2), mn2 = fminf(a, b2);
            nm[4 + i] = mx2 + flog2(1.f + fexp2(mn2 - mx2));
            // move: the other 6 sources (mask and LSE over 8; -1e30 absorbs safely in fp32)
            s[i] = -1e30f; s[i + 4] = -1e30f;
            float mx = fmaxf(fmaxf(fmaxf(s[0], s[1]), fmaxf(s[2], s[3])),
                             fmaxf(fmaxf(s[4], s[5]), fmaxf(s[6], s[7])));
            float sum = ((fexp2(s[0] - mx) + fexp2(s[1] - mx)) + (fexp2(s[2] - mx) + fexp2(s[3] - mx)))
                      + ((fexp2(s[4] - mx) + fexp2(s[5] - mx)) + (fexp2(s[6] - mx) + fexp2(s[7] - mx)));
            nm[i] = mx + flog2(sum);
        }
#pragma unroll
        for (int i = 0; i < 8; ++i) m[i] = nm[i];
#pragma unroll
        for (int q = 0; q < 8; ++q) w[q] = wn[q];
        p = pn;
    }

    float* dst = chunkM + (((size_t)batch * CCHUNK + c) * 8 + j0) * 8;
#pragma unroll
    for (int i = 0; i < 8; ++i) dst[i] = m[i];
}

// ---------------------------------------------------------------- sequential combine over chunks
__global__ __launch_bounds__(1024) void combine_k(const float* __restrict__ chunkM,
                                                  float* __restrict__ logZdiv)
{
    const int tid   = threadIdx.x;          // 128 batches * 8 lanes
    const int ip    = tid & 7;
    const int batch = tid >> 3;
    const int gbase = (tid & 63) & ~7;      // group base lane within wave

    float v[8];
#pragma unroll
    for (int j = 0; j < 8; ++j) v[j] = 0.f;   // fwd0 = zeros

    for (int c = 0; c < CCHUNK; ++c) {
        const float* Mp = chunkM + (((size_t)batch * CCHUNK + c) << 6);
        float s[8];
#pragma unroll
        for (int j = 0; j < 8; ++j) s[j] = Mp[j * 8 + ip] + v[j];  // M_c[ip][j] + v[j]
        float mx = fmaxf(fmaxf(fmaxf(s[0], s[1]), fmaxf(s[2], s[3])),
                         fmaxf(fmaxf(s[4], s[5]), fmaxf(s[6], s[7])));
        float sum = ((fexp2(s[0] - mx) + fexp2(s[1] - mx)) + (fexp2(s[2] - mx) + fexp2(s[3] - mx)))
                  + ((fexp2(s[4] - mx) + fexp2(s[5] - mx)) + (fexp2(s[6] - mx) + fexp2(s[7] - mx)));
        float nv = mx + flog2(sum);
#pragma unroll
        for (int j = 0; j < 8; ++j) v[j] = __shfl(nv, gbase + j, 64);
    }
    float mx = fmaxf(fmaxf(fmaxf(v[0], v[1]), fmaxf(v[2], v[3])),
                     fmaxf(fmaxf(v[4], v[5]), fmaxf(v[6], v[7])));
    float sum = ((fexp2(v[0] - mx) + fexp2(v[1] - mx)) + (fexp2(v[2] - mx) + fexp2(v[3] - mx)))
              + ((fexp2(v[4] - mx) + fexp2(v[5] - mx)) + (fexp2(v[6] - mx) + fexp2(v[7] - mx)));
    float r = mx + flog2(sum);
    if (ip == 0) logZdiv[batch] = r * LN2 / (float)NTIME;   // back to base-e, /ntime
}

// ---------------------------------------------------------------- subtract logZ from trans section
__global__ __launch_bounds__(256) void sub_logz(float* __restrict__ out,
                                                const float* __restrict__ logZdiv)
{
    size_t idx = (size_t)blockIdx.x * 256 + threadIdx.x;   // 2000*128*8 float4s
    size_t row = idx >> 3;
    int q = (int)(idx & 7);
    int batch = (int)(row & 127);
    float lz = logZdiv[batch];
    float4v* pp = (float4v*)(out + row * NOUT + 8 + q * 4);
    float4v vv = *pp;
    vv[0] -= lz; vv[1] -= lz; vv[2] -= lz; vv[3] -= lz;
    *pp = vv;
}

// ---------------------------------------------------------------- launch
extern "C" void kernel_launch(void* const* d_in, const int* in_sizes, int n_in,
                              void* d_out, int out_size, void* d_ws, size_t ws_size,
                              hipStream_t stream)
{
    const float* x = (const float*)d_in[0];   // (2000,128,256)
    const float* W = (const float*)d_in[1];   // (40,256)
    const float* b = (const float*)d_in[2];   // (40,)
    float* out = (float*)d_out;               // (2000,128,40)

    char* ws = (char*)d_ws;
    short* Wb      = (short*)ws;                                                 // 24576 B
    float* chunkM  = (float*)(ws + 32768);                                       // 128*80*64*4 = 2621440 B
    float* logZdiv = (float*)(ws + 32768 + (size_t)NBATCH * CCHUNK * 64 * 4);

    hipLaunchKernelGGL(prep_w,      dim3(48),        dim3(256),  0, stream, W, Wb);
    hipLaunchKernelGGL(gemm_act,    dim3(NROWS/128), dim3(256),  0, stream, x, Wb, b, out);
    hipLaunchKernelGGL(scan_chunks, dim3(CCHUNK*4),  dim3(256),  0, stream, out, chunkM);
    hipLaunchKernelGGL(combine_k,   dim3(1),         dim3(1024), 0, stream, chunkM, logZdiv);
    hipLaunchKernelGGL(sub_logz,    dim3(8000),      dim3(256),  0, stream, out, logZdiv);
}